// Round 3
// baseline (1093.151 us; speedup 1.0000x reference)
//
#include <hip/hip_runtime.h>

#define B_SZ    16384
#define T_STEPS 3
#define D_IN    2752
#define H_SZ    256
#define O_SZ    100
#define LDA     (T_STEPS * D_IN)   // 8256 floats, dvs row stride per batch row

typedef short bf16x8 __attribute__((ext_vector_type(8)));   // 8 bf16 = 4 VGPRs
typedef float f32x4  __attribute__((ext_vector_type(4)));

__device__ __forceinline__ unsigned short f2bf(float x) {
  union { float f; unsigned int u; } v; v.f = x;
  unsigned int r = v.u + 0x7FFFu + ((v.u >> 16) & 1u);   // RNE
  return (unsigned short)(r >> 16);
}

// pack two fp32 -> two truncated bf16 in one v_perm_b32
__device__ __forceinline__ unsigned int pack2_bf16_trunc(float lo, float hi) {
  union { float f; unsigned int u; } a, b;
  a.f = lo; b.f = hi;
  // pool: bytes0-3 = src1(lo), bytes4-7 = src0(hi); sel 2,3,6,7
  return __builtin_amdgcn_perm(b.u, a.u, 0x07060302u);
}

// ---------------------------------------------------------------------------
// W1 fp32 -> bf16 (RNE; layout preserved [256][2752])
// ---------------------------------------------------------------------------
__global__ void cvt_w1_kernel(const float* __restrict__ W1,
                              unsigned short* __restrict__ W1bf) {
  int i = (blockIdx.x * 256 + threadIdx.x) * 4;
  float4 v = *(const float4*)(W1 + i);
  unsigned short o[4] = {f2bf(v.x), f2bf(v.y), f2bf(v.z), f2bf(v.w)};
  *(uint2*)(W1bf + i) = *(uint2*)o;
}

// ---------------------------------------------------------------------------
// GEMM1 (bf16 MFMA, barrier-free, LDS-free):
//   Hout[(t*B+b), n] = dot(dvs[b,t,:], W1[n,:]) + b1[n]
// Block = 256 thr = 4 waves; block tile M=64 (shared via L1), each wave owns
// n in [64w,64w+64): 4x4 grid of 16x16x32 MFMAs.
// A fragments loaded fp32 from global (1 aligned 128B line per row-chunk),
// packed to bf16 via v_perm (truncate). B fragments read bf16 from L2-hot
// W1bf (1.4 MB). No __syncthreads -> compiler pipelines loads across K.
// ---------------------------------------------------------------------------
__global__ __launch_bounds__(256) void gemm1_mfma_kernel(
    const float* __restrict__ dvs, const unsigned short* __restrict__ W1bf,
    const float* __restrict__ b1, float* __restrict__ Hout) {
  const int r0   = blockIdx.x * 64;        // output row (t*B+b); 256 blocks per t
  const int t    = r0 >> 14;
  const int brow = r0 & (B_SZ - 1);

  const int lane = threadIdx.x & 63, wv = threadIdx.x >> 6;
  const int wn0  = wv * 64;
  const int lrow = lane & 15;              // row/col within a 16-tile
  const int kg   = lane >> 4;              // k-group -> k offset kg*8

  const float* abase = dvs + (size_t)brow * LDA + t * D_IN + kg * 8;
  const float* ap[4];
#pragma unroll
  for (int m = 0; m < 4; m++) ap[m] = abase + (size_t)(m * 16 + lrow) * LDA;
  const unsigned short* bp[4];
#pragma unroll
  for (int n = 0; n < 4; n++)
    bp[n] = W1bf + (size_t)(wn0 + n * 16 + lrow) * D_IN + kg * 8;

  f32x4 acc[4][4] = {};

#pragma unroll 2
  for (int k0 = 0; k0 < D_IN; k0 += 32) {   // 86 iterations
    // issue all loads for this iteration first (12 VMEM instrs, no barriers)
    float4 a0[4], a1[4];
#pragma unroll
    for (int m = 0; m < 4; m++) {
      a0[m] = *(const float4*)(ap[m] + k0);
      a1[m] = *(const float4*)(ap[m] + k0 + 4);
    }
    bf16x8 bfrag[4];
#pragma unroll
    for (int n = 0; n < 4; n++) bfrag[n] = *(const bf16x8*)(bp[n] + k0);

#pragma unroll
    for (int m = 0; m < 4; m++) {
      union { unsigned int u[4]; bf16x8 v; } cv;
      cv.u[0] = pack2_bf16_trunc(a0[m].x, a0[m].y);
      cv.u[1] = pack2_bf16_trunc(a0[m].z, a0[m].w);
      cv.u[2] = pack2_bf16_trunc(a1[m].x, a1[m].y);
      cv.u[3] = pack2_bf16_trunc(a1[m].z, a1[m].w);
#pragma unroll
      for (int n = 0; n < 4; n++)
        acc[m][n] = __builtin_amdgcn_mfma_f32_16x16x32_bf16(
            cv.v, bfrag[n], acc[m][n], 0, 0, 0);
    }
  }

  // epilogue: C layout col = lane&15, row = (lane>>4)*4 + reg
#pragma unroll
  for (int m = 0; m < 4; m++) {
    int gm = r0 + m * 16 + kg * 4;
#pragma unroll
    for (int n = 0; n < 4; n++) {
      int gn = wn0 + n * 16 + lrow;
      float bias = b1[gn];
#pragma unroll
      for (int r = 0; r < 4; r++)
        Hout[(size_t)(gm + r) * H_SZ + gn] = acc[m][n][r] + bias;
    }
  }
}

// ---------------------------------------------------------------------------
// Tiled transpose: out[c*rows + r] = in[r*cols + c]
// ---------------------------------------------------------------------------
__global__ void transpose_kernel(const float* __restrict__ in,
                                 float* __restrict__ out, int rows, int cols) {
  __shared__ float tile[32][33];
  int bc = blockIdx.x * 32, br = blockIdx.y * 32;
  int tx = threadIdx.x, ty = threadIdx.y;   // 32 x 8
  for (int j = 0; j < 32; j += 8) {
    int r = br + ty + j, c = bc + tx;
    if (r < rows && c < cols) tile[ty + j][tx] = in[(size_t)r * cols + c];
  }
  __syncthreads();
  for (int j = 0; j < 32; j += 8) {
    int c = bc + ty + j, r = br + tx;
    if (c < cols && r < rows) out[(size_t)c * rows + r] = tile[tx][ty + j];
  }
}

// ---------------------------------------------------------------------------
// Recurrent LIF chain v3: ONE WAVE PER BATCH ROW (16384 waves -> max TLP to
// hide the serialized sparse-gather latency). No LDS, no barriers.
// Spike sets as 4x u64 ballot masks; layer-2 gather = 4 coalesced 256B row
// loads per spiking neuron from L2-hot W2T; layer-3 gather ~never runs.
// ---------------------------------------------------------------------------
__global__ __launch_bounds__(256) void recurrent3_kernel(
    const float* __restrict__ H, const float* __restrict__ W2T,
    const float* __restrict__ b2, const float* __restrict__ W3T,
    const float* __restrict__ b3, float* __restrict__ out) {
  const int lane = threadIdx.x & 63;
  const int b = blockIdx.x * 4 + (threadIdx.x >> 6);

  float b2v[4];
#pragma unroll
  for (int q = 0; q < 4; q++) b2v[q] = b2[lane + 64 * q];
  const float b3a = b3[lane];
  const float b3b = (lane < O_SZ - 64) ? b3[64 + lane] : 0.f;

  float v1[4] = {0.f, 0.f, 0.f, 0.f};
  float v2[4] = {0.f, 0.f, 0.f, 0.f};
  float v3a = 0.f, v3b = 0.f, s3a = 0.f, s3b = 0.f;

  for (int t = 0; t < T_STEPS; t++) {
    const float* hp = H + ((size_t)t * B_SZ + b) * H_SZ;
    unsigned long long m1[4];
    float h2[4] = {b2v[0], b2v[1], b2v[2], b2v[3]};
#pragma unroll
    for (int q = 0; q < 4; q++) {
      float h1 = hp[lane + 64 * q];
      v1[q] = 0.5f * (v1[q] + h1);
      bool s = (v1[q] >= 1.0f);
      m1[q] = __ballot(s);
      if (s) v1[q] = 0.f;
    }
#pragma unroll
    for (int q = 0; q < 4; q++) {
      unsigned long long m = m1[q];
      while (m) {
        int n = 64 * q + __builtin_ctzll(m);
        m &= m - 1;
        const float* wp = W2T + (size_t)n * H_SZ + lane;
        h2[0] += wp[0]; h2[1] += wp[64]; h2[2] += wp[128]; h2[3] += wp[192];
      }
    }
    unsigned long long m2[4];
#pragma unroll
    for (int q = 0; q < 4; q++) {
      v2[q] = 0.5f * (v2[q] + h2[q]);
      bool s = (v2[q] >= 1.0f);
      m2[q] = __ballot(s);
      if (s) v2[q] = 0.f;
    }
    float h3a = b3a, h3b = b3b;
#pragma unroll
    for (int q = 0; q < 4; q++) {
      unsigned long long m = m2[q];
      while (m) {
        int j = 64 * q + __builtin_ctzll(m);
        m &= m - 1;
        h3a += W3T[(size_t)j * O_SZ + lane];
        if (lane < O_SZ - 64) h3b += W3T[(size_t)j * O_SZ + 64 + lane];
      }
    }
    v3a = 0.5f * (v3a + h3a);
    v3b = 0.5f * (v3b + h3b);
    bool sa = (v3a >= 1.0f), sb = (v3b >= 1.0f);
    if (sa) v3a = 0.f;
    if (sb) v3b = 0.f;
    if (t == T_STEPS - 1) { s3a = sa ? 1.f : 0.f; s3b = sb ? 1.f : 0.f; }
  }
  out[(size_t)b * O_SZ + lane] = s3a;
  if (lane < O_SZ - 64) out[(size_t)b * O_SZ + 64 + lane] = s3b;
}

// ---------------------------------------------------------------------------
extern "C" void kernel_launch(void* const* d_in, const int* in_sizes, int n_in,
                              void* d_out, int out_size, void* d_ws, size_t ws_size,
                              hipStream_t stream) {
  const float* dvs = (const float*)d_in[0];
  const float* W1  = (const float*)d_in[1];
  const float* b1  = (const float*)d_in[2];
  const float* W2  = (const float*)d_in[3];
  const float* b2  = (const float*)d_in[4];
  const float* W3  = (const float*)d_in[5];
  const float* b3  = (const float*)d_in[6];
  float* out = (float*)d_out;

  char* ws = (char*)d_ws;
  float* Hbuf = (float*)ws;                                  // 50,331,648 B
  float* W2T  = (float*)(ws + (size_t)T_STEPS * B_SZ * H_SZ * 4);
  float* W3T  = W2T + H_SZ * H_SZ;                           // [j][o], 256x100
  unsigned short* W1bf = (unsigned short*)(W3T + H_SZ * O_SZ);

  dim3 tb(32, 8);
  hipLaunchKernelGGL(cvt_w1_kernel, dim3((H_SZ * D_IN) / 1024), dim3(256),
                     0, stream, W1, W1bf);
  hipLaunchKernelGGL(transpose_kernel, dim3(8, 8), tb, 0, stream, W2, W2T, H_SZ, H_SZ);
  hipLaunchKernelGGL(transpose_kernel, dim3(8, 4), tb, 0, stream, W3, W3T, O_SZ, H_SZ);
  hipLaunchKernelGGL(gemm1_mfma_kernel, dim3((T_STEPS * B_SZ) / 64), dim3(256),
                     0, stream, dvs, W1bf, b1, Hbuf);
  hipLaunchKernelGGL(recurrent3_kernel, dim3(B_SZ / 4), dim3(256), 0, stream,
                     Hbuf, W2T, b2, W3T, b3, out);
}